// Round 3
// 1510.808 us; speedup vs baseline: 1.3773x; 1.3773x over previous
//
#include <hip/hip_runtime.h>
#include <hip/hip_bf16.h>
#include <math.h>

// ---------------------------------------------------------------------------
// VisionTransformerMoE — Round 7: latency-tolerant GEMM pipeline, NO
// global_load_lds (suspected container-killer in R5/R6).
//  * one-time weight conversion to bf16 (biases to f32) in workspace
//  * gemm2/moe2: reg-staged global->VGPR->ds_write_b128 double buffer, ONE
//    __syncthreads() per BK=64 tile, fragment-major LDS layout (chunk==tid
//    -> lane-linear conflict-free ds_write_b128/ds_read_b128),
//    FR=2 tiles for bigger grids, split-K(+f32 atomics) for N=384 GEMMs.
//  * falls back to Round-4 kernels if workspace is too small.
// ---------------------------------------------------------------------------

#define Bv   4
#define Nn   197
#define Tt   788            // Bv*Nn
#define Dd   384
#define Ll   12
#define Hh   1536
#define Ee   8
#define NCLS 1000
#define NPAT 196
#define MPAT (Bv*NPAT)      // 784
#define NSLOT (2*Tt)        // 1576 moe slots
#define KPAD 224            // keys padded to 7 chunks of 32
#define KS   232            // LDS row stride for lVT / lP (16B-aligned rows)

// converted-weight element counts
#define NQKVW ((size_t)Ll*3*Dd*Dd)        // 5,308,416
#define NPROJW ((size_t)Ll*Dd*Dd)         // 1,769,472
#define NFC1W ((size_t)(Ll/2)*Hh*Dd)      // 3,538,944
#define NFC2W ((size_t)(Ll/2)*Dd*Hh)      // 3,538,944
#define NE1W  ((size_t)(Ll/2)*Ee*Hh*Dd)   // 28,311,552
#define NE2W  ((size_t)(Ll/2)*Ee*Dd*Hh)   // 28,311,552
#define NQKVB ((size_t)Ll*3*Dd)
#define NPROJB ((size_t)Ll*Dd)
#define NFC1B ((size_t)(Ll/2)*Hh)
#define NFC2B ((size_t)(Ll/2)*Dd)
#define NE1B  ((size_t)(Ll/2)*Ee*Hh)
#define NE2B  ((size_t)(Ll/2)*Ee*Dd)

typedef __attribute__((ext_vector_type(8))) short bf16x8;
typedef __attribute__((ext_vector_type(4))) float f32x4;

static __device__ __forceinline__ short f2b(float f) {
    union { __hip_bfloat16 h; short s; } u; u.h = __float2bfloat16(f); return u.s;
}
static __device__ __forceinline__ float b2f_s(short s) {
    union { __hip_bfloat16 h; short s; } u; u.s = s; return __bfloat162float(u.h);
}
static __device__ __forceinline__ float tofl(float v) { return v; }
static __device__ __forceinline__ float tofl(__hip_bfloat16 v) { return __bfloat162float(v); }
static __device__ __forceinline__ float gelu_exact(float v) {
    return 0.5f * v * (1.0f + erff(v * 0.70710678118654752f));
}
static __device__ __forceinline__ bf16x8 load8w(const __hip_bfloat16* p) {
    return *(const bf16x8*)p;
}
static __device__ __forceinline__ bf16x8 load8w(const float* p) {
    const float4* q = (const float4*)p;
    float4 a = q[0], b = q[1];
    bf16x8 r;
    r[0]=f2b(a.x); r[1]=f2b(a.y); r[2]=f2b(a.z); r[3]=f2b(a.w);
    r[4]=f2b(b.x); r[5]=f2b(b.y); r[6]=f2b(b.z); r[7]=f2b(b.w);
    return r;
}
static __device__ __forceinline__ bf16x8 zero8() {
    bf16x8 r;
    #pragma unroll
    for (int i = 0; i < 8; i++) r[i] = 0;
    return r;
}

// ---------------- dtype detect ---------------------------------------------
__global__ void detect_kernel(const void* ln1w, int* flag)
{
    *flag = (*(const unsigned int*)ln1w == 0x3F803F80u) ? 1 : 0;
}

// ---------------- weight conversion ----------------------------------------
// blockIdx.y selects segment: 0..5 -> bf16 weights, 6..11 -> f32 biases
__global__ __launch_bounds__(256)
void cvt_kernel(const void* s0, const void* s1, const void* s2, const void* s3,
                const void* s4, const void* s5, const void* s6, const void* s7,
                const void* s8, const void* s9, const void* s10, const void* s11,
                short* w0, short* w1, short* w2, short* w3, short* w4, short* w5,
                float* f0, float* f1, float* f2, float* f3, float* f4, float* f5,
                const int* flag)
{
    int seg = blockIdx.y;
    const void* src; size_t n; short* dw = nullptr; float* df = nullptr;
    switch (seg) {
        case 0:  src = s0;  n = NQKVW;  dw = w0; break;
        case 1:  src = s1;  n = NPROJW; dw = w1; break;
        case 2:  src = s2;  n = NFC1W;  dw = w2; break;
        case 3:  src = s3;  n = NFC2W;  dw = w3; break;
        case 4:  src = s4;  n = NE1W;   dw = w4; break;
        case 5:  src = s5;  n = NE2W;   dw = w5; break;
        case 6:  src = s6;  n = NQKVB;  df = f0; break;
        case 7:  src = s7;  n = NPROJB; df = f1; break;
        case 8:  src = s8;  n = NFC1B;  df = f2; break;
        case 9:  src = s9;  n = NFC2B;  df = f3; break;
        case 10: src = s10; n = NE1B;   df = f4; break;
        default: src = s11; n = NE2B;   df = f5; break;
    }
    size_t n4 = n >> 2;
    bool isbf = (*flag != 0);
    size_t stride = (size_t)gridDim.x * 256;
    for (size_t i = (size_t)blockIdx.x * 256 + threadIdx.x; i < n4; i += stride) {
        if (dw) {
            if (isbf) {
                ((short4*)dw)[i] = ((const short4*)src)[i];
            } else {
                float4 v = ((const float4*)src)[i];
                short4 o; o.x = f2b(v.x); o.y = f2b(v.y); o.z = f2b(v.z); o.w = f2b(v.w);
                ((short4*)dw)[i] = o;
            }
        } else {
            if (isbf) {
                short4 v = ((const short4*)src)[i];
                float4 o; o.x = b2f_s(v.x); o.y = b2f_s(v.y); o.z = b2f_s(v.z); o.w = b2f_s(v.w);
                ((float4*)df)[i] = o;
            } else {
                ((float4*)df)[i] = ((const float4*)src)[i];
            }
        }
    }
}

// ---------------- im2col: Pm[784][768] bf16 --------------------------------
template<typename T>
static __device__ void im2col_body(const T* __restrict__ x, short* __restrict__ Pm)
{
    int idx = blockIdx.x * 256 + threadIdx.x;
    if (idx >= MPAT * 768) return;
    int row = idx / 768, col = idx % 768;
    int b = row / NPAT, p = row % NPAT;
    int c = col >> 8, rem = col & 255, i = rem >> 4, j = rem & 15;
    int py = p / 14, px = p % 14;
    Pm[idx] = f2b(tofl(x[(((size_t)b * 3 + c) * 224 + py * 16 + i) * 224 + px * 16 + j]));
}
__global__ __launch_bounds__(256)
void im2col_kernel(const void* x, short* Pm, const int* flag)
{
    if (*flag) im2col_body<__hip_bfloat16>((const __hip_bfloat16*)x, Pm);
    else       im2col_body<float>((const float*)x, Pm);
}

// ---------------- assemble: h = [cls|patches] + pos ------------------------
template<typename T>
static __device__ void assemble_body(const float* __restrict__ ptmp, const T* __restrict__ cls,
                                     const T* __restrict__ pos, float* __restrict__ h)
{
    int idx = blockIdx.x * 256 + threadIdx.x;
    if (idx >= Tt * Dd) return;
    int t = idx / Dd, d = idx % Dd;
    int b = t / Nn, n = t % Nn;
    float v = (n == 0) ? tofl(cls[d]) : ptmp[((size_t)b * NPAT + n - 1) * Dd + d];
    h[idx] = v + tofl(pos[(size_t)n * Dd + d]);
}
__global__ __launch_bounds__(256)
void assemble_kernel(const float* ptmp, const void* cls, const void* pos, float* h, const int* flag)
{
    if (*flag) assemble_body<__hip_bfloat16>(ptmp, (const __hip_bfloat16*)cls,
                                             (const __hip_bfloat16*)pos, h);
    else       assemble_body<float>(ptmp, (const float*)cls, (const float*)pos, h);
}

// ---------------- layernorm: 4 tokens/block, writes bf16 -------------------
template<typename T>
static __device__ void ln_body(const float* __restrict__ X, const T* __restrict__ w,
                               const T* __restrict__ bb, short* __restrict__ Y16)
{
    int t = blockIdx.x * 4 + (threadIdx.x >> 6);
    int lane = threadIdx.x & 63;
    float v[6], s = 0.f, s2 = 0.f;
    #pragma unroll
    for (int i = 0; i < 6; i++) {
        float xv = X[(size_t)t * Dd + lane + i * 64];
        v[i] = xv; s += xv; s2 += xv * xv;
    }
    #pragma unroll
    for (int off = 32; off > 0; off >>= 1) {
        s  += __shfl_xor(s, off);
        s2 += __shfl_xor(s2, off);
    }
    float mean = s * (1.f / Dd);
    float var  = s2 * (1.f / Dd) - mean * mean;
    float r = rsqrtf(var + 1e-6f);
    #pragma unroll
    for (int i = 0; i < 6; i++) {
        int d = lane + i * 64;
        Y16[(size_t)t * Dd + d] = f2b((v[i] - mean) * r * tofl(w[d]) + tofl(bb[d]));
    }
}
__global__ __launch_bounds__(256)
void ln_kernel(const float* X, const void* w, const void* bb, size_t woff,
               short* Y16, const int* flag)
{
    if (*flag) ln_body<__hip_bfloat16>(X, (const __hip_bfloat16*)w + woff,
                                       (const __hip_bfloat16*)bb + woff, Y16);
    else       ln_body<float>(X, (const float*)w + woff, (const float*)bb + woff, Y16);
}

// ---------------- Round-4 GEMM (fallback + patch embed) --------------------
template<typename WT, int FR>
static __device__ void gemm_body(const short* __restrict__ A, const WT* __restrict__ W,
                                 const WT* __restrict__ bias,
                                 float* __restrict__ Cf, short* __restrict__ Cb,
                                 const float* __restrict__ resid,
                                 int M, int N, int K, int act,
                                 short* lA, short* lB)
{
    int tid = threadIdx.x;
    int m0 = blockIdx.y * (FR * 16), n0 = blockIdx.x * 64;
    int w = tid >> 6, lane = tid & 63, quad = lane >> 4, l15 = lane & 15;
    int arow = tid >> 2, koff = (tid & 3) * 8;
    int gm = m0 + arow;
    f32x4 acc[FR];
    #pragma unroll
    for (int f = 0; f < FR; f++) acc[f] = (f32x4){0.f, 0.f, 0.f, 0.f};

    for (int k0 = 0; k0 < K; k0 += 32) {
        if (arow < FR * 16) {
            bf16x8 av = (gm < M) ? *(const bf16x8*)(A + (size_t)gm * K + k0 + koff) : zero8();
            *(bf16x8*)&lA[arow * 32 + koff] = av;
        }
        *(bf16x8*)&lB[arow * 32 + koff] = load8w(W + (size_t)(n0 + arow) * K + k0 + koff);
        __syncthreads();
        bf16x8 bfrag = *(const bf16x8*)&lB[(w * 16 + l15) * 32 + quad * 8];
        #pragma unroll
        for (int f = 0; f < FR; f++) {
            bf16x8 afrag = *(const bf16x8*)&lA[(f * 16 + l15) * 32 + quad * 8];
            acc[f] = __builtin_amdgcn_mfma_f32_16x16x32_bf16(afrag, bfrag, acc[f], 0, 0, 0);
        }
        __syncthreads();
    }
    int col = n0 + w * 16 + l15;
    float bs = tofl(bias[col]);
    #pragma unroll
    for (int f = 0; f < FR; f++) {
        #pragma unroll
        for (int r = 0; r < 4; r++) {
            int m = m0 + f * 16 + quad * 4 + r;
            if (m >= M) continue;
            float v = acc[f][r] + bs;
            if (act) v = gelu_exact(v);
            if (resid) v += resid[(size_t)m * N + col];
            if (Cf) Cf[(size_t)m * N + col] = v;
            if (Cb) Cb[(size_t)m * N + col] = f2b(v);
        }
    }
}
template<int FR>
__global__ __launch_bounds__(256)
void gemm_kernel(const short* A, const void* W, size_t woff, const void* bias, size_t boff,
                 float* Cf, short* Cb, const float* resid,
                 int M, int N, int K, int act, const int* flag)
{
    __shared__ short lA[FR * 16 * 32];
    __shared__ short lB[64 * 32];
    if (*flag) gemm_body<__hip_bfloat16, FR>(A, (const __hip_bfloat16*)W + woff,
                                             (const __hip_bfloat16*)bias + boff,
                                             Cf, Cb, resid, M, N, K, act, lA, lB);
    else       gemm_body<float, FR>(A, (const float*)W + woff, (const float*)bias + boff,
                                    Cf, Cb, resid, M, N, K, act, lA, lB);
}

// ---------------- Round-4 MoE GEMM (fallback) ------------------------------
template<typename WT>
static __device__ void moe_gemm_body(const short* __restrict__ A, const WT* __restrict__ W,
                                     const WT* __restrict__ bias,
                                     float* __restrict__ Cf, short* __restrict__ Cb,
                                     const int* __restrict__ cnt, const int* __restrict__ perm,
                                     int N, int K, int rshift, int act,
                                     int* rows, short* lA, short* lB)
{
    int e = blockIdx.z;
    int c = cnt[e];
    int r0 = blockIdx.y * 64;
    if (r0 >= c) return;
    int n0 = blockIdx.x * 64;
    int tid = threadIdx.x;
    if (tid < 64) rows[tid] = (r0 + tid < c) ? perm[e * NSLOT + r0 + tid] : -1;
    __syncthreads();
    const WT* We = W + (size_t)e * N * K;
    const WT* be = bias + (size_t)e * N;
    int w = tid >> 6, lane = tid & 63, quad = lane >> 4, l15 = lane & 15;
    int arow = tid >> 2, koff = (tid & 3) * 8;
    int slot = rows[arow];
    f32x4 acc[4];
    #pragma unroll
    for (int f = 0; f < 4; f++) acc[f] = (f32x4){0.f, 0.f, 0.f, 0.f};

    for (int k0 = 0; k0 < K; k0 += 32) {
        bf16x8 av = (slot >= 0) ? *(const bf16x8*)(A + (size_t)(slot >> rshift) * K + k0 + koff)
                                : zero8();
        *(bf16x8*)&lA[arow * 32 + koff] = av;
        *(bf16x8*)&lB[arow * 32 + koff] = load8w(We + (size_t)(n0 + arow) * K + k0 + koff);
        __syncthreads();
        bf16x8 bfrag = *(const bf16x8*)&lB[(w * 16 + l15) * 32 + quad * 8];
        #pragma unroll
        for (int f = 0; f < 4; f++) {
            bf16x8 afrag = *(const bf16x8*)&lA[(f * 16 + l15) * 32 + quad * 8];
            acc[f] = __builtin_amdgcn_mfma_f32_16x16x32_bf16(afrag, bfrag, acc[f], 0, 0, 0);
        }
        __syncthreads();
    }
    int col = n0 + w * 16 + l15;
    float bs = tofl(be[col]);
    #pragma unroll
    for (int f = 0; f < 4; f++) {
        #pragma unroll
        for (int r = 0; r < 4; r++) {
            int s2 = rows[f * 16 + quad * 4 + r];
            if (s2 < 0) continue;
            float v = acc[f][r] + bs;
            if (act) v = gelu_exact(v);
            if (Cf) Cf[(size_t)s2 * N + col] = v;
            if (Cb) Cb[(size_t)s2 * N + col] = f2b(v);
        }
    }
}
__global__ __launch_bounds__(256)
void moe_gemm(const short* A, const void* W, size_t woff, const void* bias, size_t boff,
              float* Cf, short* Cb, const int* cnt, const int* perm,
              int N, int K, int rshift, int act, const int* flag)
{
    __shared__ int rows[64];
    __shared__ short lA[64 * 32];
    __shared__ short lB[64 * 32];
    if (*flag) moe_gemm_body<__hip_bfloat16>(A, (const __hip_bfloat16*)W + woff,
                                             (const __hip_bfloat16*)bias + boff,
                                             Cf, Cb, cnt, perm, N, K, rshift, act, rows, lA, lB);
    else       moe_gemm_body<float>(A, (const float*)W + woff, (const float*)bias + boff,
                                    Cf, Cb, cnt, perm, N, K, rshift, act, rows, lA, lB);
}

// ---------------- Round-7 pipelined GEMM (bf16 W, f32 bias) ----------------
// Tile FR*16 x 64, BK=64, 4 waves. Fragment-major LDS: 16B chunk id == tid
// that stages it -> ds_write_b128 and ds_read_b128 are both lane-linear
// (0 bank conflicts). Reg-staged double buffer, ONE __syncthreads per tile:
//   load regs k+1 -> mfma(buf) -> write LDS buf^1 -> sync
// (iteration k's reads of buf drain at the sync before iteration k+1 writes).
// SK>1: grid.z splits K, partials accumulated with f32 atomics into Cf
// (bias added by z==0 only; caller guarantees act==0, Cb==null).
template<int FR, int SK>
__global__ __launch_bounds__(256)
void gemm2_kernel(const short* __restrict__ A, const short* __restrict__ W,
                  const float* __restrict__ bias,
                  float* __restrict__ Cf, short* __restrict__ Cb,
                  int M, int N, int K, int act)
{
    constexpr int BUFS = (FR * 16 + 64) * 64;   // shorts per LDS buffer
    constexpr int AIT = FR / 2;                  // A chunks per thread
    __shared__ __align__(16) short lds[2 * BUFS];

    const int tid = threadIdx.x;
    const int w = tid >> 6, lane = tid & 63, quad = lane >> 4, l15 = lane & 15;
    const int m0 = blockIdx.y * (FR * 16), n0 = blockIdx.x * 64;
    const int Kp = K / SK;
    const int kb = (SK > 1) ? blockIdx.z * Kp : 0;
    const int nk = Kp >> 6;

    // chunk c holds A[row=(c>>7)*16+(c&15)][k=((c>>6)&1)*32+((c>>4)&3)*8 ..+8]
    const short* pa[AIT];
    #pragma unroll
    for (int i = 0; i < AIT; i++) {
        int c = tid + i * 256;
        int row = ((c >> 7) << 4) + (c & 15);
        int ck  = (((c >> 6) & 1) << 5) + (((c >> 4) & 3) << 3);
        int gm = m0 + row; if (gm > M - 1) gm = M - 1;   // clamp; masked at store
        pa[i] = A + (size_t)gm * K + kb + ck;
    }
    const short* pb[2];
    #pragma unroll
    for (int i = 0; i < 2; i++) {
        int c = tid + i * 256;
        int row = ((c >> 7) << 4) + (c & 15);
        int ck  = (((c >> 6) & 1) << 5) + (((c >> 4) & 3) << 3);
        pb[i] = W + (size_t)(n0 + row) * K + kb + ck;
    }

    f32x4 acc[FR];
    #pragma unroll
    for (int f = 0; f < FR; f++) acc[f] = (f32x4){0.f, 0.f, 0.f, 0.f};

    bf16x8 ra[AIT], rb[2];
    auto loadg = [&](int kt) {
        #pragma unroll
        for (int i = 0; i < AIT; i++) ra[i] = *(const bf16x8*)(pa[i] + kt * 64);
        #pragma unroll
        for (int i = 0; i < 2; i++)  rb[i] = *(const bf16x8*)(pb[i] + kt * 64);
    };
    auto store_lds = [&](int bi) {
        short* bA = lds + bi * BUFS;
        short* bB = bA + FR * 1024;
        #pragma unroll
        for (int i = 0; i < AIT; i++) *(bf16x8*)(bA + (i * 256 + tid) * 8) = ra[i];
        #pragma unroll
        for (int i = 0; i < 2; i++)  *(bf16x8*)(bB + (i * 256 + tid) * 8) = rb[i];
    };
    auto mfma_ph = [&](int bi) {
        const short* bA = lds + bi * BUFS;
        const short* bB = bA + FR * 1024;
        bf16x8 bf[2];
        #pragma unroll
        for (int kk = 0; kk < 2; kk++)
            bf[kk] = *(const bf16x8*)(bB + ((w * 2 + kk) * 64 + lane) * 8);
        #pragma unroll
        for (int f = 0; f < FR; f++) {
            #pragma unroll
            for (int kk = 0; kk < 2; kk++) {
                bf16x8 af = *(const bf16x8*)(bA + ((f * 2 + kk) * 64 + lane) * 8);
                acc[f] = __builtin_amdgcn_mfma_f32_16x16x32_bf16(af, bf[kk], acc[f], 0, 0, 0);
            }
        }
    };

    loadg(0);
    store_lds(0);
    __syncthreads();
    int buf = 0;
    for (int k = 0; k < nk; k++) {
        if (k + 1 < nk) loadg(k + 1);      // global loads in flight under MFMAs
        mfma_ph(buf);
        if (k + 1 < nk) {
            store_lds(buf ^ 1);            // vmcnt waits inserted by compiler
            __syncthreads();
        }
        buf ^= 1;
    }

    const int col = n0 + w * 16 + l15;
    const float bs = bias[col];
    #pragma unroll
    for (int f = 0; f < FR; f++) {
        #pragma unroll
        for (int r = 0; r < 4; r++) {
            int m = m0 + f * 16 + quad * 4 + r;
            if (m >= M) continue;
            float v = acc[f][r];
            if constexpr (SK == 1) {
                v += bs;
                if (act) v = gelu_exact(v);
                if (Cb) Cb[(size_t)m * N + col] = f2b(v);
                if (Cf) Cf[(size_t)m * N + col] = v;
            } else {
                if (blockIdx.z == 0) v += bs;
                atomicAdd(&Cf[(size_t)m * N + col], v);
            }
        }
    }
}

// ---------------- Round-7 pipelined MoE GEMM -------------------------------
template<int FR>
__global__ __launch_bounds__(256)
void moe2_kernel(const short* __restrict__ A, const short* __restrict__ W,
                 const float* __restrict__ bias,
                 float* __restrict__ Cf, short* __restrict__ Cb,
                 const int* __restrict__ cnt, const int* __restrict__ perm,
                 int N, int K, int rshift, int act)
{
    constexpr int BUFS = (FR * 16 + 64) * 64;
    constexpr int AIT = FR / 2;
    __shared__ __align__(16) short lds[2 * BUFS];
    __shared__ int rows[FR * 16];

    const int e = blockIdx.z;
    const int c0 = cnt[e];
    const int r0 = blockIdx.y * (FR * 16);
    if (r0 >= c0) return;                      // uniform exit, before barriers
    const int tid = threadIdx.x;
    if (tid < FR * 16) rows[tid] = (r0 + tid < c0) ? perm[e * NSLOT + r0 + tid] : -1;
    __syncthreads();

    const short* We = W + (size_t)e * N * K;
    const float* be = bias + (size_t)e * N;
    const int w = tid >> 6, lane = tid & 63, quad = lane >> 4, l15 = lane & 15;
    const int n0 = blockIdx.x * 64;
    const int nk = K >> 6;
    const int slot0 = rows[0];                 // always valid (r0 < c0)

    const short* pa[AIT];
    #pragma unroll
    for (int i = 0; i < AIT; i++) {
        int c = tid + i * 256;
        int row = ((c >> 7) << 4) + (c & 15);
        int ck  = (((c >> 6) & 1) << 5) + (((c >> 4) & 3) << 3);
        int s = rows[row]; if (s < 0) s = slot0;   // clamp; masked at store
        pa[i] = A + (size_t)(s >> rshift) * K + ck;
    }
    const short* pb[2];
    #pragma unroll
    for (int i = 0; i < 2; i++) {
        int c = tid + i * 256;
        int row = ((c >> 7) << 4) + (c & 15);
        int ck  = (((c >> 6) & 1) << 5) + (((c >> 4) & 3) << 3);
        pb[i] = We + (size_t)(n0 + row) * K + ck;
    }

    f32x4 acc[FR];
    #pragma unroll
    for (int f = 0; f < FR; f++) acc[f] = (f32x4){0.f, 0.f, 0.f, 0.f};

    bf16x8 ra[AIT], rb[2];
    auto loadg = [&](int kt) {
        #pragma unroll
        for (int i = 0; i < AIT; i++) ra[i] = *(const bf16x8*)(pa[i] + kt * 64);
        #pragma unroll
        for (int i = 0; i < 2; i++)  rb[i] = *(const bf16x8*)(pb[i] + kt * 64);
    };
    auto store_lds = [&](int bi) {
        short* bA = lds + bi * BUFS;
        short* bB = bA + FR * 1024;
        #pragma unroll
        for (int i = 0; i < AIT; i++) *(bf16x8*)(bA + (i * 256 + tid) * 8) = ra[i];
        #pragma unroll
        for (int i = 0; i < 2; i++)  *(bf16x8*)(bB + (i * 256 + tid) * 8) = rb[i];
    };
    auto mfma_ph = [&](int bi) {
        const short* bA = lds + bi * BUFS;
        const short* bB = bA + FR * 1024;
        bf16x8 bf[2];
        #pragma unroll
        for (int kk = 0; kk < 2; kk++)
            bf[kk] = *(const bf16x8*)(bB + ((w * 2 + kk) * 64 + lane) * 8);
        #pragma unroll
        for (int f = 0; f < FR; f++) {
            #pragma unroll
            for (int kk = 0; kk < 2; kk++) {
                bf16x8 af = *(const bf16x8*)(bA + ((f * 2 + kk) * 64 + lane) * 8);
                acc[f] = __builtin_amdgcn_mfma_f32_16x16x32_bf16(af, bf[kk], acc[f], 0, 0, 0);
            }
        }
    };

    loadg(0);
    store_lds(0);
    __syncthreads();
    int buf = 0;
    for (int k = 0; k < nk; k++) {
        if (k + 1 < nk) loadg(k + 1);
        mfma_ph(buf);
        if (k + 1 < nk) {
            store_lds(buf ^ 1);
            __syncthreads();
        }
        buf ^= 1;
    }

    const int col = n0 + w * 16 + l15;
    const float bs = be[col];
    #pragma unroll
    for (int f = 0; f < FR; f++) {
        #pragma unroll
        for (int r = 0; r < 4; r++) {
            int s2 = rows[f * 16 + quad * 4 + r];
            if (s2 < 0) continue;
            float v = acc[f][r] + bs;
            if (act) v = gelu_exact(v);
            if (Cb) Cb[(size_t)s2 * N + col] = f2b(v);
            if (Cf) Cf[(size_t)s2 * N + col] = v;
        }
    }
}

// ---------------- MFMA flash attention -------------------------------------
__global__ __launch_bounds__(256)
void attn_kernel(const short* __restrict__ qkv16, short* __restrict__ att16)
{
    __shared__ short lVT[64 * KS];       // V^T: [d][key], zero-padded keys
    __shared__ short lP[4 * 16 * KS];    // per-wave P: [query][key]
    int qt = blockIdx.x, hh = blockIdx.y, b = blockIdx.z;
    int tid = threadIdx.x;
    int w = tid >> 6, lane = tid & 63, quad = lane >> 4, l15 = lane & 15;
    const int bq = b * Nn;
    const int rs = 3 * Dd;               // 1152

    for (int idx = tid; idx < 64 * KPAD; idx += 256) {
        int d = idx & 63, j = idx >> 6;
        short v = (j < Nn) ? qkv16[(size_t)(bq + j) * rs + 2 * Dd + hh * 64 + d] : (short)0;
        lVT[d * KS + j] = v;
    }
    __syncthreads();

    int q0w = qt * 64 + w * 16;
    int qi = q0w + l15;
    size_t qrow = (size_t)(bq + (qi < Nn ? qi : Nn - 1)) * rs + hh * 64;
    bf16x8 a0 = *(const bf16x8*)(qkv16 + qrow + quad * 8);
    bf16x8 a1 = *(const bf16x8*)(qkv16 + qrow + 32 + quad * 8);

    f32x4 sr[13];
    #pragma unroll
    for (int nt = 0; nt < 13; nt++) {
        int key = nt * 16 + l15;
        size_t krow = (size_t)(bq + (key < Nn ? key : Nn - 1)) * rs + Dd + hh * 64;
        bf16x8 b0 = *(const bf16x8*)(qkv16 + krow + quad * 8);
        bf16x8 b1 = *(const bf16x8*)(qkv16 + krow + 32 + quad * 8);
        f32x4 s = (f32x4){0.f, 0.f, 0.f, 0.f};
        s = __builtin_amdgcn_mfma_f32_16x16x32_bf16(a0, b0, s, 0, 0, 0);
        s = __builtin_amdgcn_mfma_f32_16x16x32_bf16(a1, b1, s, 0, 0, 0);
        bool valid = key < Nn;
        #pragma unroll
        for (int r = 0; r < 4; r++) sr[nt][r] = valid ? s[r] * 0.125f : -1e30f;
    }

    float mrow[4], lrow[4], inv[4];
    #pragma unroll
    for (int r = 0; r < 4; r++) {
        float m = -1e30f;
        #pragma unroll
        for (int nt = 0; nt < 13; nt++) m = fmaxf(m, sr[nt][r]);
        #pragma unroll
        for (int off = 1; off < 16; off <<= 1) m = fmaxf(m, __shfl_xor(m, off));
        mrow[r] = m;
        lrow[r] = 0.f;
    }
    #pragma unroll
    for (int nt = 0; nt < 13; nt++) {
        #pragma unroll
        for (int r = 0; r < 4; r++) {
            float ev = expf(sr[nt][r] - mrow[r]);
            lrow[r] += ev;
            lP[(w * 16 + quad * 4 + r) * KS + nt * 16 + l15] = f2b(ev);
        }
    }
    #pragma unroll
    for (int r = 0; r < 4; r++) {
        float s = lrow[r];
        #pragma unroll
        for (int off = 1; off < 16; off <<= 1) s += __shfl_xor(s, off);
        inv[r] = 1.f / s;
        lP[(w * 16 + quad * 4 + r) * KS + 208 + l15] = 0;
    }

    #pragma unroll
    for (int dt = 0; dt < 4; dt++) {
        f32x4 acc = (f32x4){0.f, 0.f, 0.f, 0.f};
        #pragma unroll
        for (int kc = 0; kc < 7; kc++) {
            bf16x8 ap = *(const bf16x8*)&lP[(w * 16 + l15) * KS + kc * 32 + quad * 8];
            bf16x8 bp = *(const bf16x8*)&lVT[(dt * 16 + l15) * KS + kc * 32 + quad * 8];
            acc = __builtin_amdgcn_mfma_f32_16x16x32_bf16(ap, bp, acc, 0, 0, 0);
        }
        #pragma unroll
        for (int r = 0; r < 4; r++) {
            int q = q0w + quad * 4 + r;
            if (q < Nn)
                att16[(size_t)(bq + q) * Dd + hh * 64 + dt * 16 + l15] = f2b(acc[r] * inv[r]);
        }
    }
}

// ---------------- MoE gate --------------------------------------------------
template<typename WT>
static __device__ void gate_body(const short* __restrict__ Y16, const WT* __restrict__ GW,
                                 float* __restrict__ gw_out,
                                 int* __restrict__ cnt, int* __restrict__ perm)
{
    int t = blockIdx.x;
    int lane = threadIdx.x;
    float part[Ee] = {};
    #pragma unroll
    for (int i = 0; i < 6; i++) {
        float yv = b2f_s(Y16[(size_t)t * Dd + lane + i * 64]);
        #pragma unroll
        for (int e = 0; e < Ee; e++)
            part[e] += yv * tofl(GW[(size_t)e * Dd + lane + i * 64]);
    }
    #pragma unroll
    for (int off = 32; off > 0; off >>= 1)
        #pragma unroll
        for (int e = 0; e < Ee; e++) part[e] += __shfl_xor(part[e], off);
    if (lane == 0) {
        int i0 = 0;
        for (int e = 1; e < Ee; e++) if (part[e] > part[i0]) i0 = e;
        int i1 = -1;
        for (int e = 0; e < Ee; e++) {
            if (e == i0) continue;
            if (i1 < 0 || part[e] > part[i1]) i1 = e;
        }
        float e1 = expf(part[i1] - part[i0]);
        float denom = 1.f / (1.f + e1);
        gw_out[t * 2]     = denom;
        gw_out[t * 2 + 1] = e1 * denom;
        int p0 = atomicAdd(&cnt[i0], 1); perm[i0 * NSLOT + p0] = t * 2;
        int p1 = atomicAdd(&cnt[i1], 1); perm[i1 * NSLOT + p1] = t * 2 + 1;
    }
}
__global__ __launch_bounds__(64)
void gate_kernel(const short* Y16, const void* GW, size_t goff, float* gw_out,
                 int* cnt, int* perm, const int* flag)
{
    if (*flag) gate_body<__hip_bfloat16>(Y16, (const __hip_bfloat16*)GW + goff, gw_out, cnt, perm);
    else       gate_body<float>(Y16, (const float*)GW + goff, gw_out, cnt, perm);
}

// ---------------- MoE combine ----------------------------------------------
__global__ __launch_bounds__(256)
void moe_combine(float* __restrict__ h, const float* __restrict__ moeb,
                 const float* __restrict__ gw)
{
    int idx = blockIdx.x * 256 + threadIdx.x;
    if (idx >= Tt * Dd) return;
    int t = idx / Dd, d = idx % Dd;
    h[idx] += gw[t * 2] * moeb[(size_t)(t * 2) * Dd + d]
            + gw[t * 2 + 1] * moeb[(size_t)(t * 2 + 1) * Dd + d];
}

// ---------------- classification head --------------------------------------
template<typename WT>
static __device__ void head_body(const short* __restrict__ Y16, const WT* __restrict__ hw,
                                 const WT* __restrict__ hb, WT* __restrict__ out)
{
    int idx = blockIdx.x * 256 + threadIdx.x;
    if (idx >= Bv * NCLS) return;
    int b = idx / NCLS, c = idx % NCLS;
    const short* y = Y16 + (size_t)b * Nn * Dd;
    const WT* w = hw + (size_t)c * Dd;
    float acc = 0.f;
    #pragma unroll 8
    for (int k = 0; k < Dd; k++) acc += b2f_s(y[k]) * tofl(w[k]);
    float r = acc + tofl(hb[c]);
    if (sizeof(WT) == 2) { union { __hip_bfloat16 h; WT w2; } u; u.h = __float2bfloat16(r); out[idx] = u.w2; }
    else                 { union { float f; WT w2; } u; u.f = r; out[idx] = u.w2; }
}
__global__ __launch_bounds__(256)
void head_kernel(const short* Y16, const void* hw, const void* hb, void* out, const int* flag)
{
    if (*flag) head_body<__hip_bfloat16>(Y16, (const __hip_bfloat16*)hw, (const __hip_bfloat16*)hb,
                                         (__hip_bfloat16*)out);
    else       head_body<float>(Y16, (const float*)hw, (const float*)hb, (float*)out);
}

// ---------------------------------------------------------------------------
extern "C" void kernel_launch(void* const* d_in, const int* in_sizes, int n_in,
                              void* d_out, int out_size, void* d_ws, size_t ws_size,
                              hipStream_t stream)
{
    const void* x       = d_in[0];
    const void* patch_w = d_in[1];
    const void* patch_b = d_in[2];
    const void* cls_tok = d_in[3];
    const void* pos_emb = d_in[4];
    const void* ln1_w   = d_in[5];
    const void* ln1_b   = d_in[6];
    const void* qkv_w   = d_in[7];
    const void* qkv_b   = d_in[8];
    const void* proj_w  = d_in[9];
    const void* proj_b  = d_in[10];
    const void* ln2_w   = d_in[11];
    const void* ln2_b   = d_in[12];
    const void* fc1_w   = d_in[13];
    const void* fc1_b   = d_in[14];
    const void* fc2_w   = d_in[15];
    const void* fc2_b   = d_in[16];
    const void* gate_w  = d_in[17];
    const void* e1_w    = d_in[18];
    const void* e1_b    = d_in[19];
    const void* e2_w    = d_in[20];
    const void* e2_b    = d_in[21];
    const void* lnf_w   = d_in[22];
    const void* lnf_b   = d_in[23];
    const void* head_w  = d_in[24];
    const void* head_b  = d_in[25];

    // ---- workspace layout ----
    char* p = (char*)d_ws;
    auto alloc = [&](size_t bytes) { char* r = p; p += (bytes + 255) & ~(size_t)255; return r; };
    float* h     = (float*)alloc((size_t)Tt * Dd * 4);
    short* y16   = (short*)alloc((size_t)Tt * Dd * 2);
    short* qkv16 = (short*)alloc((size_t)Tt * 3 * Dd * 2);
    short* att16 = (short*)alloc((size_t)Tt * Dd * 2);
    short* hid16 = (short*)alloc((size_t)NSLOT * Hh * 2);
    float* moeb  = (float*)alloc((size_t)NSLOT * Dd * 4);
    float* gw    = (float*)alloc((size_t)NSLOT * 4);
    int*   cnt   = (int*)alloc(Ee * 4);
    int*   perm  = (int*)alloc((size_t)Ee * NSLOT * 4);
    int*   flag  = (int*)alloc(4);
    short* Pm    = (short*)alloc((size_t)MPAT * 768 * 2);
    float* ptmp  = (float*)alloc((size_t)MPAT * Dd * 4);
    // converted weights
    short* wq  = (short*)alloc(NQKVW * 2);
    short* wp  = (short*)alloc(NPROJW * 2);
    short* w1c = (short*)alloc(NFC1W * 2);
    short* w2c = (short*)alloc(NFC2W * 2);
    short* we1 = (short*)alloc(NE1W * 2);
    short* we2 = (short*)alloc(NE2W * 2);
    float* bq  = (float*)alloc(NQKVB * 4);
    float* bp  = (float*)alloc(NPROJB * 4);
    float* b1c = (float*)alloc(NFC1B * 4);
    float* b2c = (float*)alloc(NFC2B * 4);
    float* be1 = (float*)alloc(NE1B * 4);
    float* be2 = (float*)alloc(NE2B * 4);
    const int use_cvt = ((size_t)(p - (char*)d_ws) <= ws_size);

    dim3 blk(256);
    detect_kernel<<<1, 1, 0, stream>>>(ln1_w, flag);

    if (use_cvt) {
        cvt_kernel<<<dim3(512, 12), blk, 0, stream>>>(
            qkv_w, proj_w, fc1_w, fc2_w, e1_w, e2_w,
            qkv_b, proj_b, fc1_b, fc2_b, e1_b, e2_b,
            wq, wp, w1c, w2c, we1, we2, bq, bp, b1c, b2c, be1, be2, flag);
    }

    // patch embed as GEMM: Pm[784,768] @ patch_w[384,768]^T + pb -> ptmp
    im2col_kernel<<<(MPAT * 768 + 255) / 256, blk, 0, stream>>>(x, Pm, flag);
    gemm_kernel<2><<<dim3(Dd / 64, (MPAT + 31) / 32), blk, 0, stream>>>(
        Pm, patch_w, 0, patch_b, 0, ptmp, nullptr, nullptr, MPAT, Dd, 768, 0, flag);
    assemble_kernel<<<(Tt * Dd + 255) / 256, blk, 0, stream>>>(ptmp, cls_tok, pos_emb, h, flag);

    const int MB4 = (Tt + 63) / 64;      // 13
    const int MB2 = (Tt + 31) / 32;      // 25
    const int MBS = (NSLOT + 63) / 64;   // 25 (worst-case expert load, FR=4)
    const int MBS2 = (NSLOT + 31) / 32;  // 50 (FR=2)

    for (int l = 0; l < Ll; l++) {
        int m = l / 2;
        // --- attention ---
        ln_kernel<<<Tt / 4, blk, 0, stream>>>(h, ln1_w, ln1_b, (size_t)l * Dd, y16, flag);
        if (use_cvt) {
            gemm2_kernel<2, 1><<<dim3(3 * Dd / 64, MB2), blk, 0, stream>>>(
                y16, wq + (size_t)l * 3 * Dd * Dd, bq + (size_t)l * 3 * Dd,
                nullptr, qkv16, Tt, 3 * Dd, Dd, 0);
        } else {
            gemm_kernel<4><<<dim3(3 * Dd / 64, MB4), blk, 0, stream>>>(
                y16, qkv_w, (size_t)l * 3 * Dd * Dd, qkv_b, (size_t)l * 3 * Dd,
                nullptr, qkv16, nullptr, Tt, 3 * Dd, Dd, 0, flag);
        }
        attn_kernel<<<dim3(4, 6, Bv), blk, 0, stream>>>(qkv16, att16);
        if (use_cvt) {
            // split-K=2, f32-atomic accumulate into h (h already holds residual)
            gemm2_kernel<2, 2><<<dim3(Dd / 64, MB2, 2), blk, 0, stream>>>(
                att16, wp + (size_t)l * Dd * Dd, bp + (size_t)l * Dd,
                h, nullptr, Tt, Dd, Dd, 0);
        } else {
            gemm_kernel<2><<<dim3(Dd / 64, MB2), blk, 0, stream>>>(
                att16, proj_w, (size_t)l * Dd * Dd, proj_b, (size_t)l * Dd,
                h, nullptr, h, Tt, Dd, Dd, 0, flag);
        }
        // --- ffn ---
        ln_kernel<<<Tt / 4, blk, 0, stream>>>(h, ln2_w, ln2_b, (size_t)l * Dd, y16, flag);
        if (l % 2 == 0) {
            if (use_cvt) {
                gemm2_kernel<2, 1><<<dim3(Hh / 64, MB2), blk, 0, stream>>>(
                    y16, w1c + (size_t)m * Hh * Dd, b1c + (size_t)m * Hh,
                    nullptr, hid16, Tt, Hh, Dd, 1);
                gemm2_kernel<2, 4><<<dim3(Dd / 64, MB2, 4), blk, 0, stream>>>(
                    hid16, w2c + (size_t)m * Dd * Hh, b2c + (size_t)m * Dd,
                    h, nullptr, Tt, Dd, Hh, 0);
            } else {
                gemm_kernel<4><<<dim3(Hh / 64, MB4), blk, 0, stream>>>(
                    y16, fc1_w, (size_t)m * Hh * Dd, fc1_b, (size_t)m * Hh,
                    nullptr, hid16, nullptr, Tt, Hh, Dd, 1, flag);
                gemm_kernel<2><<<dim3(Dd / 64, MB2), blk, 0, stream>>>(
                    hid16, fc2_w, (size_t)m * Dd * Hh, fc2_b, (size_t)m * Dd,
                    h, nullptr, h, Tt, Dd, Hh, 0, flag);
            }
        } else {
            hipMemsetAsync(cnt, 0, Ee * sizeof(int), stream);
            gate_kernel<<<Tt, 64, 0, stream>>>(
                y16, gate_w, (size_t)m * Ee * Dd, gw, cnt, perm, flag);
            if (use_cvt) {
                moe2_kernel<4><<<dim3(Hh / 64, MBS, Ee), blk, 0, stream>>>(
                    y16, we1 + (size_t)m * Ee * Hh * Dd, be1 + (size_t)m * Ee * Hh,
                    nullptr, hid16, cnt, perm, Hh, Dd, 1, 1);
                moe2_kernel<2><<<dim3(Dd / 64, MBS2, Ee), blk, 0, stream>>>(
                    hid16, we2 + (size_t)m * Ee * Dd * Hh, be2 + (size_t)m * Ee * Dd,
                    moeb, nullptr, cnt, perm, Dd, Hh, 0, 0);
            } else {
                moe_gemm<<<dim3(Hh / 64, MBS, Ee), blk, 0, stream>>>(
                    y16, e1_w, (size_t)m * Ee * Hh * Dd, e1_b, (size_t)m * Ee * Hh,
                    nullptr, hid16, cnt, perm, Hh, Dd, 1, 1, flag);
                moe_gemm<<<dim3(Dd / 64, MBS, Ee), blk, 0, stream>>>(
                    hid16, e2_w, (size_t)m * Ee * Dd * Hh, e2_b, (size_t)m * Ee * Dd,
                    moeb, nullptr, cnt, perm, Dd, Hh, 0, 0, flag);
            }
            moe_combine<<<(Tt * Dd + 255) / 256, blk, 0, stream>>>(h, moeb, gw);
        }
    }

    ln_kernel<<<Tt / 4, blk, 0, stream>>>(h, lnf_w, lnf_b, 0, y16, flag);
    head_kernel<<<(Bv * NCLS + 255) / 256, blk, 0, stream>>>(y16, head_w, head_b, d_out, flag);
}

// Round 4
// 1397.526 us; speedup vs baseline: 1.4890x; 1.0811x over previous
//
#include <hip/hip_runtime.h>
#include <hip/hip_bf16.h>
#include <math.h>

// ---------------------------------------------------------------------------
// VisionTransformerMoE — Round 8.
//  R7 (1511 us) + :
//  * cvt2: flat load-balanced weight conversion (one linear chunk space,
//    constexpr segment boundaries, static pointers) — was 118us @2.4TB/s
//    due to 25x segment imbalance; also converts patch_w -> gemm2 path.
//  * odd layers: ln2+gate fused (no atomics, writes sel+weights), 1-block
//    build kernel replaces memset+gate, moe-combine fused into e2 epilogue.
//  * final LN computes only the 4 cls tokens.
//  * gemm2/moe2: 2-deep register prefetch (2 reg sets) — issue->wait
//    distance = 1 full iteration of MFMA+store+sync.
//  * falls back to Round-4 kernels if workspace is too small.
// ---------------------------------------------------------------------------

#define Bv   4
#define Nn   197
#define Tt   788            // Bv*Nn
#define Dd   384
#define Ll   12
#define Hh   1536
#define Ee   8
#define NCLS 1000
#define NPAT 196
#define MPAT (Bv*NPAT)      // 784
#define NSLOT (2*Tt)        // 1576 moe slots
#define KPAD 224            // keys padded to 7 chunks of 32
#define KS   232            // LDS row stride for lVT / lP (16B-aligned rows)

// converted-weight element counts
#define NQKVW ((size_t)Ll*3*Dd*Dd)        // 5,308,416
#define NPROJW ((size_t)Ll*Dd*Dd)         // 1,769,472
#define NFC1W ((size_t)(Ll/2)*Hh*Dd)      // 3,538,944
#define NFC2W ((size_t)(Ll/2)*Dd*Hh)      // 3,538,944
#define NE1W  ((size_t)(Ll/2)*Ee*Hh*Dd)   // 28,311,552
#define NE2W  ((size_t)(Ll/2)*Ee*Dd*Hh)   // 28,311,552
#define NPW   ((size_t)Dd*768)            // 294,912
#define NQKVB ((size_t)Ll*3*Dd)           // 13,824
#define NPROJB ((size_t)Ll*Dd)            // 4,608
#define NFC1B ((size_t)(Ll/2)*Hh)         // 9,216
#define NFC2B ((size_t)(Ll/2)*Dd)         // 2,304
#define NE1B  ((size_t)(Ll/2)*Ee*Hh)      // 73,728
#define NE2B  ((size_t)(Ll/2)*Ee*Dd)      // 18,432
#define NPB   ((size_t)Dd)                // 384

typedef __attribute__((ext_vector_type(8))) short bf16x8;
typedef __attribute__((ext_vector_type(4))) float f32x4;

static __device__ __forceinline__ short f2b(float f) {
    union { __hip_bfloat16 h; short s; } u; u.h = __float2bfloat16(f); return u.s;
}
static __device__ __forceinline__ float b2f_s(short s) {
    union { __hip_bfloat16 h; short s; } u; u.s = s; return __bfloat162float(u.h);
}
static __device__ __forceinline__ float tofl(float v) { return v; }
static __device__ __forceinline__ float tofl(__hip_bfloat16 v) { return __bfloat162float(v); }
static __device__ __forceinline__ float gelu_exact(float v) {
    return 0.5f * v * (1.0f + erff(v * 0.70710678118654752f));
}
static __device__ __forceinline__ bf16x8 load8w(const __hip_bfloat16* p) {
    return *(const bf16x8*)p;
}
static __device__ __forceinline__ bf16x8 load8w(const float* p) {
    const float4* q = (const float4*)p;
    float4 a = q[0], b = q[1];
    bf16x8 r;
    r[0]=f2b(a.x); r[1]=f2b(a.y); r[2]=f2b(a.z); r[3]=f2b(a.w);
    r[4]=f2b(b.x); r[5]=f2b(b.y); r[6]=f2b(b.z); r[7]=f2b(b.w);
    return r;
}
static __device__ __forceinline__ bf16x8 zero8() {
    bf16x8 r;
    #pragma unroll
    for (int i = 0; i < 8; i++) r[i] = 0;
    return r;
}

// ---------------- dtype detect ---------------------------------------------
__global__ void detect_kernel(const void* ln1w, int* flag)
{
    *flag = (*(const unsigned int*)ln1w == 0x3F803F80u) ? 1 : 0;
}

// ---------------- flat balanced weight conversion --------------------------
static __device__ __forceinline__ void cvt_w4(const void* src, short* dst, size_t i, bool isbf) {
    if (isbf) {
        ((short4*)dst)[i] = ((const short4*)src)[i];
    } else {
        float4 v = ((const float4*)src)[i];
        short4 o; o.x = f2b(v.x); o.y = f2b(v.y); o.z = f2b(v.z); o.w = f2b(v.w);
        ((short4*)dst)[i] = o;
    }
}
static __device__ __forceinline__ void cvt_b4(const void* src, float* dst, size_t i, bool isbf) {
    if (isbf) {
        short4 v = ((const short4*)src)[i];
        float4 o; o.x = b2f_s(v.x); o.y = b2f_s(v.y); o.z = b2f_s(v.z); o.w = b2f_s(v.w);
        ((float4*)dst)[i] = o;
    } else {
        ((float4*)dst)[i] = ((const float4*)src)[i];
    }
}
// cumulative boundaries in float4-chunk units
#define CV1  (NQKVW/4)                    //  1,327,104
#define CV2  (CV1 + NPROJW/4)             //  1,769,472
#define CV3  (CV2 + NFC1W/4)              //  2,654,208
#define CV4  (CV3 + NFC2W/4)              //  3,538,944
#define CV5  (CV4 + NE1W/4)               // 10,616,832
#define CV6  (CV5 + NE2W/4)               // 17,694,720
#define CV7  (CV6 + NPW/4)                // 17,768,448
#define CV8  (CV7 + NQKVB/4)
#define CV9  (CV8 + NPROJB/4)
#define CV10 (CV9 + NFC1B/4)
#define CV11 (CV10 + NFC2B/4)
#define CV12 (CV11 + NE1B/4)
#define CV13 (CV12 + NE2B/4)
#define CVT_TOT (CV13 + NPB/4)
__global__ __launch_bounds__(256)
void cvt2_kernel(const void* sq, const void* sp, const void* s1, const void* s2,
                 const void* se1, const void* se2, const void* spw,
                 const void* bq_, const void* bp_, const void* b1_, const void* b2_,
                 const void* be1_, const void* be2_, const void* bpw_,
                 short* wq, short* wp, short* w1c, short* w2c, short* we1, short* we2,
                 short* wpc,
                 float* bq, float* bp, float* b1c, float* b2c, float* be1, float* be2,
                 float* bpc, const int* flag)
{
    bool isbf = (*flag != 0);
    size_t stride = (size_t)gridDim.x * 256;
    for (size_t i = (size_t)blockIdx.x * 256 + threadIdx.x; i < CVT_TOT; i += stride) {
        if      (i < CV1)  cvt_w4(sq,  wq,  i,        isbf);
        else if (i < CV2)  cvt_w4(sp,  wp,  i - CV1,  isbf);
        else if (i < CV3)  cvt_w4(s1,  w1c, i - CV2,  isbf);
        else if (i < CV4)  cvt_w4(s2,  w2c, i - CV3,  isbf);
        else if (i < CV5)  cvt_w4(se1, we1, i - CV4,  isbf);
        else if (i < CV6)  cvt_w4(se2, we2, i - CV5,  isbf);
        else if (i < CV7)  cvt_w4(spw, wpc, i - CV6,  isbf);
        else if (i < CV8)  cvt_b4(bq_, bq,  i - CV7,  isbf);
        else if (i < CV9)  cvt_b4(bp_, bp,  i - CV8,  isbf);
        else if (i < CV10) cvt_b4(b1_, b1c, i - CV9,  isbf);
        else if (i < CV11) cvt_b4(b2_, b2c, i - CV10, isbf);
        else if (i < CV12) cvt_b4(be1_, be1, i - CV11, isbf);
        else if (i < CV13) cvt_b4(be2_, be2, i - CV12, isbf);
        else               cvt_b4(bpw_, bpc, i - CV13, isbf);
    }
}

// ---------------- im2col: Pm[784][768] bf16 --------------------------------
template<typename T>
static __device__ void im2col_body(const T* __restrict__ x, short* __restrict__ Pm)
{
    int idx = blockIdx.x * 256 + threadIdx.x;
    if (idx >= MPAT * 768) return;
    int row = idx / 768, col = idx % 768;
    int b = row / NPAT, p = row % NPAT;
    int c = col >> 8, rem = col & 255, i = rem >> 4, j = rem & 15;
    int py = p / 14, px = p % 14;
    Pm[idx] = f2b(tofl(x[(((size_t)b * 3 + c) * 224 + py * 16 + i) * 224 + px * 16 + j]));
}
__global__ __launch_bounds__(256)
void im2col_kernel(const void* x, short* Pm, const int* flag)
{
    if (*flag) im2col_body<__hip_bfloat16>((const __hip_bfloat16*)x, Pm);
    else       im2col_body<float>((const float*)x, Pm);
}

// ---------------- assemble: h = [cls|patches] + pos ------------------------
template<typename T>
static __device__ void assemble_body(const float* __restrict__ ptmp, const T* __restrict__ cls,
                                     const T* __restrict__ pos, float* __restrict__ h)
{
    int idx = blockIdx.x * 256 + threadIdx.x;
    if (idx >= Tt * Dd) return;
    int t = idx / Dd, d = idx % Dd;
    int b = t / Nn, n = t % Nn;
    float v = (n == 0) ? tofl(cls[d]) : ptmp[((size_t)b * NPAT + n - 1) * Dd + d];
    h[idx] = v + tofl(pos[(size_t)n * Dd + d]);
}
__global__ __launch_bounds__(256)
void assemble_kernel(const float* ptmp, const void* cls, const void* pos, float* h, const int* flag)
{
    if (*flag) assemble_body<__hip_bfloat16>(ptmp, (const __hip_bfloat16*)cls,
                                             (const __hip_bfloat16*)pos, h);
    else       assemble_body<float>(ptmp, (const float*)cls, (const float*)pos, h);
}

// ---------------- layernorm: 4 tokens/block, writes bf16 -------------------
template<typename T>
static __device__ void ln_body(const float* __restrict__ X, const T* __restrict__ w,
                               const T* __restrict__ bb, short* __restrict__ Y16)
{
    int t = blockIdx.x * 4 + (threadIdx.x >> 6);
    int lane = threadIdx.x & 63;
    float v[6], s = 0.f, s2 = 0.f;
    #pragma unroll
    for (int i = 0; i < 6; i++) {
        float xv = X[(size_t)t * Dd + lane + i * 64];
        v[i] = xv; s += xv; s2 += xv * xv;
    }
    #pragma unroll
    for (int off = 32; off > 0; off >>= 1) {
        s  += __shfl_xor(s, off);
        s2 += __shfl_xor(s2, off);
    }
    float mean = s * (1.f / Dd);
    float var  = s2 * (1.f / Dd) - mean * mean;
    float r = rsqrtf(var + 1e-6f);
    #pragma unroll
    for (int i = 0; i < 6; i++) {
        int d = lane + i * 64;
        Y16[(size_t)t * Dd + d] = f2b((v[i] - mean) * r * tofl(w[d]) + tofl(bb[d]));
    }
}
__global__ __launch_bounds__(256)
void ln_kernel(const float* X, const void* w, const void* bb, size_t woff,
               short* Y16, const int* flag)
{
    if (*flag) ln_body<__hip_bfloat16>(X, (const __hip_bfloat16*)w + woff,
                                       (const __hip_bfloat16*)bb + woff, Y16);
    else       ln_body<float>(X, (const float*)w + woff, (const float*)bb + woff, Y16);
}

// ---------------- fused ln2 + gate (odd layers) -----------------------------
template<typename T>
static __device__ void ln_gate_body(const float* __restrict__ X, const T* __restrict__ w,
                                    const T* __restrict__ bb, short* __restrict__ Y16,
                                    const T* __restrict__ GW,
                                    float* __restrict__ gwo, int* __restrict__ sel)
{
    int t = blockIdx.x * 4 + (threadIdx.x >> 6);
    int lane = threadIdx.x & 63;
    float v[6], s = 0.f, s2 = 0.f;
    #pragma unroll
    for (int i = 0; i < 6; i++) {
        float xv = X[(size_t)t * Dd + lane + i * 64];
        v[i] = xv; s += xv; s2 += xv * xv;
    }
    #pragma unroll
    for (int off = 32; off > 0; off >>= 1) {
        s  += __shfl_xor(s, off);
        s2 += __shfl_xor(s2, off);
    }
    float mean = s * (1.f / Dd);
    float var  = s2 * (1.f / Dd) - mean * mean;
    float r = rsqrtf(var + 1e-6f);
    float part[Ee] = {};
    #pragma unroll
    for (int i = 0; i < 6; i++) {
        int d = lane + i * 64;
        float yv = (v[i] - mean) * r * tofl(w[d]) + tofl(bb[d]);
        Y16[(size_t)t * Dd + d] = f2b(yv);
        #pragma unroll
        for (int e = 0; e < Ee; e++)
            part[e] += yv * tofl(GW[(size_t)e * Dd + d]);
    }
    #pragma unroll
    for (int off = 32; off > 0; off >>= 1)
        #pragma unroll
        for (int e = 0; e < Ee; e++) part[e] += __shfl_xor(part[e], off);
    if (lane == 0) {
        int i0 = 0;
        for (int e = 1; e < Ee; e++) if (part[e] > part[i0]) i0 = e;
        int i1 = -1;
        for (int e = 0; e < Ee; e++) {
            if (e == i0) continue;
            if (i1 < 0 || part[e] > part[i1]) i1 = e;
        }
        float e1 = expf(part[i1] - part[i0]);
        float denom = 1.f / (1.f + e1);
        gwo[t * 2]     = denom;
        gwo[t * 2 + 1] = e1 * denom;
        sel[t * 2]     = i0;
        sel[t * 2 + 1] = i1;
    }
}
__global__ __launch_bounds__(256)
void ln_gate_kernel(const float* X, const void* w, const void* bb, size_t woff,
                    short* Y16, const void* GW, size_t goff,
                    float* gwo, int* sel, const int* flag)
{
    if (*flag) ln_gate_body<__hip_bfloat16>(X, (const __hip_bfloat16*)w + woff,
                                            (const __hip_bfloat16*)bb + woff, Y16,
                                            (const __hip_bfloat16*)GW + goff, gwo, sel);
    else       ln_gate_body<float>(X, (const float*)w + woff, (const float*)bb + woff, Y16,
                                   (const float*)GW + goff, gwo, sel);
}

// ---------------- build cnt/perm from sel (single block, LDS histogram) ----
__global__ __launch_bounds__(256)
void build_kernel(const int* __restrict__ sel, int* __restrict__ cnt, int* __restrict__ perm)
{
    __shared__ int lc[Ee];
    int tid = threadIdx.x;
    if (tid < Ee) lc[tid] = 0;
    __syncthreads();
    for (int t = tid; t < Tt; t += 256) {
        int e0 = sel[t * 2], e1 = sel[t * 2 + 1];
        int p0 = atomicAdd(&lc[e0], 1); perm[e0 * NSLOT + p0] = t * 2;
        int p1 = atomicAdd(&lc[e1], 1); perm[e1 * NSLOT + p1] = t * 2 + 1;
    }
    __syncthreads();
    if (tid < Ee) cnt[tid] = lc[tid];
}

// ---------------- Round-4 GEMM (fallback) ----------------------------------
template<typename WT, int FR>
static __device__ void gemm_body(const short* __restrict__ A, const WT* __restrict__ W,
                                 const WT* __restrict__ bias,
                                 float* __restrict__ Cf, short* __restrict__ Cb,
                                 const float* __restrict__ resid,
                                 int M, int N, int K, int act,
                                 short* lA, short* lB)
{
    int tid = threadIdx.x;
    int m0 = blockIdx.y * (FR * 16), n0 = blockIdx.x * 64;
    int w = tid >> 6, lane = tid & 63, quad = lane >> 4, l15 = lane & 15;
    int arow = tid >> 2, koff = (tid & 3) * 8;
    int gm = m0 + arow;
    f32x4 acc[FR];
    #pragma unroll
    for (int f = 0; f < FR; f++) acc[f] = (f32x4){0.f, 0.f, 0.f, 0.f};

    for (int k0 = 0; k0 < K; k0 += 32) {
        if (arow < FR * 16) {
            bf16x8 av = (gm < M) ? *(const bf16x8*)(A + (size_t)gm * K + k0 + koff) : zero8();
            *(bf16x8*)&lA[arow * 32 + koff] = av;
        }
        *(bf16x8*)&lB[arow * 32 + koff] = load8w(W + (size_t)(n0 + arow) * K + k0 + koff);
        __syncthreads();
        bf16x8 bfrag = *(const bf16x8*)&lB[(w * 16 + l15) * 32 + quad * 8];
        #pragma unroll
        for (int f = 0; f < FR; f++) {
            bf16x8 afrag = *(const bf16x8*)&lA[(f * 16 + l15) * 32 + quad * 8];
            acc[f] = __builtin_amdgcn_mfma_f32_16x16x32_bf16(afrag, bfrag, acc[f], 0, 0, 0);
        }
        __syncthreads();
    }
    int col = n0 + w * 16 + l15;
    float bs = tofl(bias[col]);
    #pragma unroll
    for (int f = 0; f < FR; f++) {
        #pragma unroll
        for (int r = 0; r < 4; r++) {
            int m = m0 + f * 16 + quad * 4 + r;
            if (m >= M) continue;
            float v = acc[f][r] + bs;
            if (act) v = gelu_exact(v);
            if (resid) v += resid[(size_t)m * N + col];
            if (Cf) Cf[(size_t)m * N + col] = v;
            if (Cb) Cb[(size_t)m * N + col] = f2b(v);
        }
    }
}
template<int FR>
__global__ __launch_bounds__(256)
void gemm_kernel(const short* A, const void* W, size_t woff, const void* bias, size_t boff,
                 float* Cf, short* Cb, const float* resid,
                 int M, int N, int K, int act, const int* flag)
{
    __shared__ short lA[FR * 16 * 32];
    __shared__ short lB[64 * 32];
    if (*flag) gemm_body<__hip_bfloat16, FR>(A, (const __hip_bfloat16*)W + woff,
                                             (const __hip_bfloat16*)bias + boff,
                                             Cf, Cb, resid, M, N, K, act, lA, lB);
    else       gemm_body<float, FR>(A, (const float*)W + woff, (const float*)bias + boff,
                                    Cf, Cb, resid, M, N, K, act, lA, lB);
}

// ---------------- Round-4 MoE GEMM (fallback) ------------------------------
template<typename WT>
static __device__ void moe_gemm_body(const short* __restrict__ A, const WT* __restrict__ W,
                                     const WT* __restrict__ bias,
                                     float* __restrict__ Cf, short* __restrict__ Cb,
                                     const int* __restrict__ cnt, const int* __restrict__ perm,
                                     int N, int K, int rshift, int act,
                                     int* rows, short* lA, short* lB)
{
    int e = blockIdx.z;
    int c = cnt[e];
    int r0 = blockIdx.y * 64;
    if (r0 >= c) return;
    int n0 = blockIdx.x * 64;
    int tid = threadIdx.x;
    if (tid < 64) rows[tid] = (r0 + tid < c) ? perm[e * NSLOT + r0 + tid] : -1;
    __syncthreads();
    const WT* We = W + (size_t)e * N * K;
    const WT* be = bias + (size_t)e * N;
    int w = tid >> 6, lane = tid & 63, quad = lane >> 4, l15 = lane & 15;
    int arow = tid >> 2, koff = (tid & 3) * 8;
    int slot = rows[arow];
    f32x4 acc[4];
    #pragma unroll
    for (int f = 0; f < 4; f++) acc[f] = (f32x4){0.f, 0.f, 0.f, 0.f};

    for (int k0 = 0; k0 < K; k0 += 32) {
        bf16x8 av = (slot >= 0) ? *(const bf16x8*)(A + (size_t)(slot >> rshift) * K + k0 + koff)
                                : zero8();
        *(bf16x8*)&lA[arow * 32 + koff] = av;
        *(bf16x8*)&lB[arow * 32 + koff] = load8w(We + (size_t)(n0 + arow) * K + k0 + koff);
        __syncthreads();
        bf16x8 bfrag = *(const bf16x8*)&lB[(w * 16 + l15) * 32 + quad * 8];
        #pragma unroll
        for (int f = 0; f < 4; f++) {
            bf16x8 afrag = *(const bf16x8*)&lA[(f * 16 + l15) * 32 + quad * 8];
            acc[f] = __builtin_amdgcn_mfma_f32_16x16x32_bf16(afrag, bfrag, acc[f], 0, 0, 0);
        }
        __syncthreads();
    }
    int col = n0 + w * 16 + l15;
    float bs = tofl(be[col]);
    #pragma unroll
    for (int f = 0; f < 4; f++) {
        #pragma unroll
        for (int r = 0; r < 4; r++) {
            int s2 = rows[f * 16 + quad * 4 + r];
            if (s2 < 0) continue;
            float v = acc[f][r] + bs;
            if (act) v = gelu_exact(v);
            if (Cf) Cf[(size_t)s2 * N + col] = v;
            if (Cb) Cb[(size_t)s2 * N + col] = f2b(v);
        }
    }
}
__global__ __launch_bounds__(256)
void moe_gemm(const short* A, const void* W, size_t woff, const void* bias, size_t boff,
              float* Cf, short* Cb, const int* cnt, const int* perm,
              int N, int K, int rshift, int act, const int* flag)
{
    __shared__ int rows[64];
    __shared__ short lA[64 * 32];
    __shared__ short lB[64 * 32];
    if (*flag) moe_gemm_body<__hip_bfloat16>(A, (const __hip_bfloat16*)W + woff,
                                             (const __hip_bfloat16*)bias + boff,
                                             Cf, Cb, cnt, perm, N, K, rshift, act, rows, lA, lB);
    else       moe_gemm_body<float>(A, (const float*)W + woff, (const float*)bias + boff,
                                    Cf, Cb, cnt, perm, N, K, rshift, act, rows, lA, lB);
}

// ---------------- Round-8 pipelined GEMM (bf16 W, f32 bias) ----------------
// Tile FR*16 x 64, BK=64, 4 waves. Fragment-major LDS (chunk==tid ->
// lane-linear conflict-free ds_write_b128/ds_read_b128). 2-deep register
// prefetch: two alternating reg sets; tile k+1's loads issued one full
// iteration (MFMA+store+sync) before the ds_write that consumes them.
// SK>1: grid.z splits K, partials accumulated with f32 atomics into Cf.
template<int FR, int SK>
__global__ __launch_bounds__(256)
void gemm2_kernel(const short* __restrict__ A, const short* __restrict__ W,
                  const float* __restrict__ bias,
                  float* __restrict__ Cf, short* __restrict__ Cb,
                  int M, int N, int K, int act)
{
    constexpr int BUFS = (FR * 16 + 64) * 64;   // shorts per LDS buffer
    constexpr int AIT = FR / 2;                  // A chunks per thread
    __shared__ __align__(16) short lds[2 * BUFS];

    const int tid = threadIdx.x;
    const int w = tid >> 6, lane = tid & 63, quad = lane >> 4, l15 = lane & 15;
    const int m0 = blockIdx.y * (FR * 16), n0 = blockIdx.x * 64;
    const int Kp = K / SK;
    const int kb = (SK > 1) ? blockIdx.z * Kp : 0;
    const int nk = Kp >> 6;

    // chunk c holds A[row=(c>>7)*16+(c&15)][k=((c>>6)&1)*32+((c>>4)&3)*8 ..+8]
    const short* pa[AIT];
    #pragma unroll
    for (int i = 0; i < AIT; i++) {
        int c = tid + i * 256;
        int row = ((c >> 7) << 4) + (c & 15);
        int ck  = (((c >> 6) & 1) << 5) + (((c >> 4) & 3) << 3);
        int gm = m0 + row; if (gm > M - 1) gm = M - 1;   // clamp; masked at store
        pa[i] = A + (size_t)gm * K + kb + ck;
    }
    const short* pb[2];
    #pragma unroll
    for (int i = 0; i < 2; i++) {
        int c = tid + i * 256;
        int row = ((c >> 7) << 4) + (c & 15);
        int ck  = (((c >> 6) & 1) << 5) + (((c >> 4) & 3) << 3);
        pb[i] = W + (size_t)(n0 + row) * K + kb + ck;
    }

    f32x4 acc[FR];
    #pragma unroll
    for (int f = 0; f < FR; f++) acc[f] = (f32x4){0.f, 0.f, 0.f, 0.f};

    bf16x8 raA[AIT], rbA[2], raB[AIT], rbB[2];
    auto loadg2 = [&](bf16x8 (&ra)[AIT], bf16x8 (&rb)[2], int kt) {
        #pragma unroll
        for (int i = 0; i < AIT; i++) ra[i] = *(const bf16x8*)(pa[i] + (size_t)kt * 64);
        #pragma unroll
        for (int i = 0; i < 2; i++)  rb[i] = *(const bf16x8*)(pb[i] + (size_t)kt * 64);
    };
    auto store2 = [&](int bi, bf16x8 (&ra)[AIT], bf16x8 (&rb)[2]) {
        short* bA = lds + bi * BUFS;
        short* bB = bA + FR * 1024;
        #pragma unroll
        for (int i = 0; i < AIT; i++) *(bf16x8*)(bA + (i * 256 + tid) * 8) = ra[i];
        #pragma unroll
        for (int i = 0; i < 2; i++)  *(bf16x8*)(bB + (i * 256 + tid) * 8) = rb[i];
    };
    auto mfma_ph = [&](int bi) {
        const short* bA = lds + bi * BUFS;
        const short* bB = bA + FR * 1024;
        bf16x8 bf[2];
        #pragma unroll
        for (int kk = 0; kk < 2; kk++)
            bf[kk] = *(const bf16x8*)(bB + ((w * 2 + kk) * 64 + lane) * 8);
        #pragma unroll
        for (int f = 0; f < FR; f++) {
            #pragma unroll
            for (int kk = 0; kk < 2; kk++) {
                bf16x8 af = *(const bf16x8*)(bA + ((f * 2 + kk) * 64 + lane) * 8);
                acc[f] = __builtin_amdgcn_mfma_f32_16x16x32_bf16(af, bf[kk], acc[f], 0, 0, 0);
            }
        }
    };

    loadg2(raA, rbA, 0);
    if (nk > 1) loadg2(raB, rbB, 1);
    store2(0, raA, rbA);
    __syncthreads();
    int buf = 0, k = 0;
    for (; k + 1 < nk; k += 2) {
        // iter k: tile k+1 waits in B set; far tile k+2 -> A set
        if (k + 2 < nk) loadg2(raA, rbA, k + 2);
        mfma_ph(buf);
        store2(buf ^ 1, raB, rbB);
        __syncthreads();
        buf ^= 1;
        // iter k+1: tile k+2 waits in A set; far tile k+3 -> B set
        if (k + 3 < nk) loadg2(raB, rbB, k + 3);
        mfma_ph(buf);
        if (k + 2 < nk) { store2(buf ^ 1, raA, rbA); __syncthreads(); }
        buf ^= 1;
    }
    if (k < nk) mfma_ph(buf);

    const int col = n0 + w * 16 + l15;
    const float bs = bias[col];
    #pragma unroll
    for (int f = 0; f < FR; f++) {
        #pragma unroll
        for (int r = 0; r < 4; r++) {
            int m = m0 + f * 16 + quad * 4 + r;
            if (m >= M) continue;
            float v = acc[f][r];
            if constexpr (SK == 1) {
                v += bs;
                if (act) v = gelu_exact(v);
                if (Cb) Cb[(size_t)m * N + col] = f2b(v);
                if (Cf) Cf[(size_t)m * N + col] = v;
            } else {
                if (blockIdx.z == 0) v += bs;
                atomicAdd(&Cf[(size_t)m * N + col], v);
            }
        }
    }
}

// ---------------- Round-8 pipelined MoE GEMM -------------------------------
// gw2 != null => fused combine: h[(slot>>1)*N+col] += gw2[slot]*(acc+bias)
template<int FR>
__global__ __launch_bounds__(256)
void moe2_kernel(const short* __restrict__ A, const short* __restrict__ W,
                 const float* __restrict__ bias,
                 float* __restrict__ Cf, short* __restrict__ Cb,
                 const int* __restrict__ cnt, const int* __restrict__ perm,
                 int N, int K, int rshift, int act,
                 const float* __restrict__ gw2, float* __restrict__ hcomb)
{
    constexpr int BUFS = (FR * 16 + 64) * 64;
    constexpr int AIT = FR / 2;
    __shared__ __align__(16) short lds[2 * BUFS];
    __shared__ int rows[FR * 16];

    const int e = blockIdx.z;
    const int c0 = cnt[e];
    const int r0 = blockIdx.y * (FR * 16);
    if (r0 >= c0) return;                      // uniform exit, before barriers
    const int tid = threadIdx.x;
    if (tid < FR * 16) rows[tid] = (r0 + tid < c0) ? perm[e * NSLOT + r0 + tid] : -1;
    __syncthreads();

    const short* We = W + (size_t)e * N * K;
    const float* be = bias + (size_t)e * N;
    const int w = tid >> 6, lane = tid & 63, quad = lane >> 4, l15 = lane & 15;
    const int n0 = blockIdx.x * 64;
    const int nk = K >> 6;
    const int slot0 = rows[0];                 // always valid (r0 < c0)

    const short* pa[AIT];
    #pragma unroll
    for (int i = 0; i < AIT; i++) {
        int c = tid + i * 256;
        int row = ((c >> 7) << 4) + (c & 15);
        int ck  = (((c >> 6) & 1) << 5) + (((c >> 4) & 3) << 3);
        int s = rows[row]; if (s < 0) s = slot0;   // clamp; masked at store
        pa[i] = A + (size_t)(s >> rshift) * K + ck;
    }
    const short* pb[2];
    #pragma unroll
    for (int i = 0; i < 2; i++) {
        int c = tid + i * 256;
        int row = ((c >> 7) << 4) + (c & 15);
        int ck  = (((c >> 6) & 1) << 5) + (((c >> 4) & 3) << 3);
        pb[i] = We + (size_t)(n0 + row) * K + ck;
    }

    f32x4 acc[FR];
    #pragma unroll
    for (int f = 0; f < FR; f++) acc[f] = (f32x4){0.f, 0.f, 0.f, 0.f};

    bf16x8 raA[AIT], rbA[2], raB[AIT], rbB[2];
    auto loadg2 = [&](bf16x8 (&ra)[AIT], bf16x8 (&rb)[2], int kt) {
        #pragma unroll
        for (int i = 0; i < AIT; i++) ra[i] = *(const bf16x8*)(pa[i] + (size_t)kt * 64);
        #pragma unroll
        for (int i = 0; i < 2; i++)  rb[i] = *(const bf16x8*)(pb[i] + (size_t)kt * 64);
    };
    auto store2 = [&](int bi, bf16x8 (&ra)[AIT], bf16x8 (&rb)[2]) {
        short* bA = lds + bi * BUFS;
        short* bB = bA + FR * 1024;
        #pragma unroll
        for (int i = 0; i < AIT; i++) *(bf16x8*)(bA + (i * 256 + tid) * 8) = ra[i];
        #pragma unroll
        for (int i = 0; i < 2; i++)  *(bf16x8*)(bB + (i * 256 + tid) * 8) = rb[i];
    };
    auto mfma_ph = [&](int bi) {
        const short* bA = lds + bi * BUFS;
        const short* bB = bA + FR * 1024;
        bf16x8 bf[2];
        #pragma unroll
        for (int kk = 0; kk < 2; kk++)
            bf[kk] = *(const bf16x8*)(bB + ((w * 2 + kk) * 64 + lane) * 8);
        #pragma unroll
        for (int f = 0; f < FR; f++) {
            #pragma unroll
            for (int kk = 0; kk < 2; kk++) {
                bf16x8 af = *(const bf16x8*)(bA + ((f * 2 + kk) * 64 + lane) * 8);
                acc[f] = __builtin_amdgcn_mfma_f32_16x16x32_bf16(af, bf[kk], acc[f], 0, 0, 0);
            }
        }
    };

    loadg2(raA, rbA, 0);
    if (nk > 1) loadg2(raB, rbB, 1);
    store2(0, raA, rbA);
    __syncthreads();
    int buf = 0, k = 0;
    for (; k + 1 < nk; k += 2) {
        if (k + 2 < nk) loadg2(raA, rbA, k + 2);
        mfma_ph(buf);
        store2(buf ^ 1, raB, rbB);
        __syncthreads();
        buf ^= 1;
        if (k + 3 < nk) loadg2(raB, rbB, k + 3);
        mfma_ph(buf);
        if (k + 2 < nk) { store2(buf ^ 1, raA, rbA); __syncthreads(); }
        buf ^= 1;
    }
    if (k < nk) mfma_ph(buf);

    const int col = n0 + w * 16 + l15;
    const float bs = be[col];
    #pragma unroll
    for (int f = 0; f < FR; f++) {
        #pragma unroll
        for (int r = 0; r < 4; r++) {
            int s2 = rows[f * 16 + quad * 4 + r];
            if (s2 < 0) continue;
            float v = acc[f][r] + bs;
            if (act) v = gelu_exact(v);
            if (gw2) {
                atomicAdd(&hcomb[(size_t)(s2 >> 1) * N + col], gw2[s2] * v);
            } else {
                if (Cb) Cb[(size_t)s2 * N + col] = f2b(v);
                if (Cf) Cf[(size_t)s2 * N + col] = v;
            }
        }
    }
}

// ---------------- MFMA flash attention -------------------------------------
__global__ __launch_bounds__(256)
void attn_kernel(const short* __restrict__ qkv16, short* __restrict__ att16)
{
    __shared__ short lVT[64 * KS];       // V^T: [d][key], zero-padded keys
    __shared__ short lP[4 * 16 * KS];    // per-wave P: [query][key]
    int qt = blockIdx.x, hh = blockIdx.y, b = blockIdx.z;
    int tid = threadIdx.x;
    int w = tid >> 6, lane = tid & 63, quad = lane >> 4, l15 = lane & 15;
    const int bq = b * Nn;
    const int rs = 3 * Dd;               // 1152

    for (int idx = tid; idx < 64 * KPAD; idx += 256) {
        int d = idx & 63, j = idx >> 6;
        short v = (j < Nn) ? qkv16[(size_t)(bq + j) * rs + 2 * Dd + hh * 64 + d] : (short)0;
        lVT[d * KS + j] = v;
    }
    __syncthreads();

    int q0w = qt * 64 + w * 16;
    int qi = q0w + l15;
    size_t qrow = (size_t)(bq + (qi < Nn ? qi : Nn - 1)) * rs + hh * 64;
    bf16x8 a0 = *(const bf16x8*)(qkv16 + qrow + quad * 8);
    bf16x8 a1 = *(const bf16x8*)(qkv16 + qrow + 32 + quad * 8);

    f32x4 sr[13];
    #pragma unroll
    for (int nt = 0; nt < 13; nt++) {
        int key = nt * 16 + l15;
        size_t krow = (size_t)(bq + (key < Nn ? key : Nn - 1)) * rs + Dd + hh * 64;
        bf16x8 b0 = *(const bf16x8*)(qkv16 + krow + quad * 8);
        bf16x8 b1 = *(const bf16x8*)(qkv16 + krow + 32 + quad * 8);
        f32x4 s = (f32x4){0.f, 0.f, 0.f, 0.f};
        s = __builtin_amdgcn_mfma_f32_16x16x32_bf16(a0, b0, s, 0, 0, 0);
        s = __builtin_amdgcn_mfma_f32_16x16x32_bf16(a1, b1, s, 0, 0, 0);
        bool valid = key < Nn;
        #pragma unroll
        for (int r = 0; r < 4; r++) sr[nt][r] = valid ? s[r] * 0.125f : -1e30f;
    }

    float mrow[4], lrow[4], inv[4];
    #pragma unroll
    for (int r = 0; r < 4; r++) {
        float m = -1e30f;
        #pragma unroll
        for (int nt = 0; nt < 13; nt++) m = fmaxf(m, sr[nt][r]);
        #pragma unroll
        for (int off = 1; off < 16; off <<= 1) m = fmaxf(m, __shfl_xor(m, off));
        mrow[r] = m;
        lrow[r] = 0.f;
    }
    #pragma unroll
    for (int nt = 0; nt < 13; nt++) {
        #pragma unroll
        for (int r = 0; r < 4; r++) {
            float ev = expf(sr[nt][r] - mrow[r]);
            lrow[r] += ev;
            lP[(w * 16 + quad * 4 + r) * KS + nt * 16 + l15] = f2b(ev);
        }
    }
    #pragma unroll
    for (int r = 0; r < 4; r++) {
        float s = lrow[r];
        #pragma unroll
        for (int off = 1; off < 16; off <<= 1) s += __shfl_xor(s, off);
        inv[r] = 1.f / s;
        lP[(w * 16 + quad * 4 + r) * KS + 208 + l15] = 0;
    }

    #pragma unroll
    for (int dt = 0; dt < 4; dt++) {
        f32x4 acc = (f32x4){0.f, 0.f, 0.f, 0.f};
        #pragma unroll
        for (int kc = 0; kc < 7; kc++) {
            bf16x8 ap = *(const bf16x8*)&lP[(w * 16 + l15) * KS + kc * 32 + quad * 8];
            bf16x8 bp = *(const bf16x8*)&lVT[(dt * 16 + l15) * KS + kc * 32 + quad * 8];
            acc = __builtin_amdgcn_mfma_f32_16x16x32_bf16(ap, bp, acc, 0, 0, 0);
        }
        #pragma unroll
        for (int r = 0; r < 4; r++) {
            int q = q0w + quad * 4 + r;
            if (q < Nn)
                att16[(size_t)(bq + q) * Dd + hh * 64 + dt * 16 + l15] = f2b(acc[r] * inv[r]);
        }
    }
}

// ---------------- MoE gate (fallback) ---------------------------------------
template<typename WT>
static __device__ void gate_body(const short* __restrict__ Y16, const WT* __restrict__ GW,
                                 float* __restrict__ gw_out,
                                 int* __restrict__ cnt, int* __restrict__ perm)
{
    int t = blockIdx.x;
    int lane = threadIdx.x;
    float part[Ee] = {};
    #pragma unroll
    for (int i = 0; i < 6; i++) {
        float yv = b2f_s(Y16[(size_t)t * Dd + lane + i * 64]);
        #pragma unroll
        for (int e = 0; e < Ee; e++)
            part[e] += yv * tofl(GW[(size_t)e * Dd + lane + i * 64]);
    }
    #pragma unroll
    for (int off = 32; off > 0; off >>= 1)
        #pragma unroll
        for (int e = 0; e < Ee; e++) part[e] += __shfl_xor(part[e], off);
    if (lane == 0) {
        int i0 = 0;
        for (int e = 1; e < Ee; e++) if (part[e] > part[i0]) i0 = e;
        int i1 = -1;
        for (int e = 0; e < Ee; e++) {
            if (e == i0) continue;
            if (i1 < 0 || part[e] > part[i1]) i1 = e;
        }
        float e1 = expf(part[i1] - part[i0]);
        float denom = 1.f / (1.f + e1);
        gw_out[t * 2]     = denom;
        gw_out[t * 2 + 1] = e1 * denom;
        int p0 = atomicAdd(&cnt[i0], 1); perm[i0 * NSLOT + p0] = t * 2;
        int p1 = atomicAdd(&cnt[i1], 1); perm[i1 * NSLOT + p1] = t * 2 + 1;
    }
}
__global__ __launch_bounds__(64)
void gate_kernel(const short* Y16, const void* GW, size_t goff, float* gw_out,
                 int* cnt, int* perm, const int* flag)
{
    if (*flag) gate_body<__hip_bfloat16>(Y16, (const __hip_bfloat16*)GW + goff, gw_out, cnt, perm);
    else       gate_body<float>(Y16, (const float*)GW + goff, gw_out, cnt, perm);
}

// ---------------- MoE combine (fallback) ------------------------------------
__global__ __launch_bounds__(256)
void moe_combine(float* __restrict__ h, const float* __restrict__ moeb,
                 const float* __restrict__ gw)
{
    int idx = blockIdx.x * 256 + threadIdx.x;
    if (idx >= Tt * Dd) return;
    int t = idx / Dd, d = idx % Dd;
    h[idx] += gw[t * 2] * moeb[(size_t)(t * 2) * Dd + d]
            + gw[t * 2 + 1] * moeb[(size_t)(t * 2 + 1) * Dd + d];
}

// ---------------- final LN on the 4 cls tokens only ------------------------
template<typename T>
static __device__ void lncls_body(const float* __restrict__ X, const T* __restrict__ w,
                                  const T* __restrict__ bb, short* __restrict__ Y16)
{
    int b = threadIdx.x >> 6;            // 4 waves, one batch each
    int lane = threadIdx.x & 63;
    size_t t = (size_t)b * Nn;
    float v[6], s = 0.f, s2 = 0.f;
    #pragma unroll
    for (int i = 0; i < 6; i++) {
        float xv = X[t * Dd + lane + i * 64];
        v[i] = xv; s += xv; s2 += xv * xv;
    }
    #pragma unroll
    for (int off = 32; off > 0; off >>= 1) {
        s  += __shfl_xor(s, off);
        s2 += __shfl_xor(s2, off);
    }
    float mean = s * (1.f / Dd);
    float var  = s2 * (1.f / Dd) - mean * mean;
    float r = rsqrtf(var + 1e-6f);
    #pragma unroll
    for (int i = 0; i < 6; i++) {
        int d = lane + i * 64;
        Y16[t * Dd + d] = f2b((v[i] - mean) * r * tofl(w[d]) + tofl(bb[d]));
    }
}
__global__ __launch_bounds__(256)
void lncls_kernel(const float* X, const void* w, const void* bb, short* Y16, const int* flag)
{
    if (*flag) lncls_body<__hip_bfloat16>(X, (const __hip_bfloat16*)w,
                                          (const __hip_bfloat16*)bb, Y16);
    else       lncls_body<float>(X, (const float*)w, (const float*)bb, Y16);
}

// ---------------- classification head --------------------------------------
template<typename WT>
static __device__ void head_body(const short* __restrict__ Y16, const WT* __restrict__ hw,
                                 const WT* __restrict__ hb, WT* __restrict__ out)
{
    int idx = blockIdx.x * 256 + threadIdx.x;
    if (idx >= Bv * NCLS) return;
    int b = idx / NCLS, c = idx % NCLS;
    const short* y = Y16 + (size_t)b * Nn * Dd;
    const WT* w = hw + (size_t)c * Dd;
    float acc = 0.f;
    #pragma unroll 8
    for (int k = 0; k < Dd; k++) acc += b2f_s(y[k]) * tofl(w[k]);
    float r = acc + tofl(hb[c]);
    if (sizeof(WT) == 2) { union { __hip_bfloat16 h; WT w2; } u; u.h = __float2bfloat16(r); out[idx] = u.w2; }
    else                 { union { float f; WT w2; } u; u.f = r; out[idx] = u.w2; }
}
__global__ __launch_bounds__(256)
void head_kernel(const short* Y16, const void* hw, const void* hb, void* out, const int* flag)
{
    if (*flag) head_body<__hip_bfloat16>(Y16, (const __hip_bfloat16*)hw, (const __hip_bfloat16*)hb,
                                         (__hip_bfloat16*)out);
    else       head_body<float>(Y16, (const float*)hw, (const float*)hb, (float*)out);
}

// ---------------------------------------------------------------------------
extern "C" void kernel_launch(void* const* d_in, const int* in_sizes, int n_in,
                              void* d_out, int out_size, void* d_ws, size_t ws_size,
                              hipStream_t stream)
{
    const void* x       = d_in[0];
    const void* patch_w = d_in[1];
    const void* patch_b = d_in[2];
    const void* cls_tok = d_in[3];
    const void* pos_emb = d_in[4];
    const void* ln1_w   = d_in[5];
    const void* ln1_b   = d_in[6];
    const void* qkv_w   = d_in[7];
    const void* qkv_b   = d_in[8];
    const void* proj_w  = d_in[9];
    const void* proj_b  = d_in[10];
    const void* ln2_w   = d_in[11];
    const void* ln2_b   = d_in[12];
    const void* fc1_w   = d_in[13];
    const void* fc1_b   = d_in[14];
    const void* fc2_w   = d_in[15];
    const void* fc2_b   = d_in[16];
    const void* gate_w  = d_in[17];
    const void* e1_w    = d_in[18];
    const void* e1_b    = d_in[19];
    const void* e2_w    = d_in[20];
    const void* e2_b    = d_in[21];
    const void* lnf_w   = d_in[22];
    const void* lnf_b   = d_in[23];
    const void* head_w  = d_in[24];
    const void* head_b  = d_in[25];

    // ---- workspace layout ----
    char* p = (char*)d_ws;
    auto alloc = [&](size_t bytes) { char* r = p; p += (bytes + 255) & ~(size_t)255; return r; };
    float* h     = (float*)alloc((size_t)Tt * Dd * 4);
    short* y16   = (short*)alloc((size_t)Tt * Dd * 2);
    short* qkv16 = (short*)alloc((size_t)Tt * 3 * Dd * 2);
    short* att16 = (short*)alloc((size_t)Tt * Dd * 2);
    short* hid16 = (short*)alloc((size_t)NSLOT * Hh * 2);
    float* moeb  = (float*)alloc((size_t)NSLOT * Dd * 4);
    float* gw    = (float*)alloc((size_t)NSLOT * 4);
    int*   cnt   = (int*)alloc(Ee * 4);
    int*   perm  = (int*)alloc((size_t)Ee * NSLOT * 4);
    int*   sel   = (int*)alloc((size_t)NSLOT * 4);
    int*   flag  = (int*)alloc(4);
    short* Pm    = (short*)alloc((size_t)MPAT * 768 * 2);
    float* ptmp  = (float*)alloc((size_t)MPAT * Dd * 4);
    // converted weights
    short* wq  = (short*)alloc(NQKVW * 2);
    short* wp  = (short*)alloc(NPROJW * 2);
    short* w1c = (short*)alloc(NFC1W * 2);
    short* w2c = (short*)alloc(NFC2W * 2);
    short* we1 = (short*)alloc(NE1W * 2);
    short* we2 = (short*)alloc(NE2W * 2);
    short* wpc = (short*)alloc(NPW * 2);
    float* bq  = (float*)alloc(NQKVB * 4);
    float* bp  = (float*)alloc(NPROJB * 4);
    float* b1c = (float*)alloc(NFC1B * 4);
    float* b2c = (float*)alloc(NFC2B * 4);
    float* be1 = (float*)alloc(NE1B * 4);
    float* be2 = (float*)alloc(NE2B * 4);
    float* bpc = (float*)alloc(NPB * 4);
    const int use_cvt = ((size_t)(p - (char*)d_ws) <= ws_size);

    dim3 blk(256);
    detect_kernel<<<1, 1, 0, stream>>>(ln1_w, flag);

    if (use_cvt) {
        cvt2_kernel<<<4096, blk, 0, stream>>>(
            qkv_w, proj_w, fc1_w, fc2_w, e1_w, e2_w, patch_w,
            qkv_b, proj_b, fc1_b, fc2_b, e1_b, e2_b, patch_b,
            wq, wp, w1c, w2c, we1, we2, wpc,
            bq, bp, b1c, b2c, be1, be2, bpc, flag);
    }

    // patch embed as GEMM: Pm[784,768] @ patch_w[384,768]^T + pb -> ptmp
    im2col_kernel<<<(MPAT * 768 + 255) / 256, blk, 0, stream>>>(x, Pm, flag);
    if (use_cvt) {
        gemm2_kernel<2, 1><<<dim3(Dd / 64, (MPAT + 31) / 32), blk, 0, stream>>>(
            Pm, wpc, bpc, ptmp, nullptr, MPAT, Dd, 768, 0);
    } else {
        gemm_kernel<2><<<dim3(Dd / 64, (MPAT + 31) / 32), blk, 0, stream>>>(
            Pm, patch_w, 0, patch_b, 0, ptmp, nullptr, nullptr, MPAT, Dd, 768, 0, flag);
    }
    assemble_kernel<<<(Tt * Dd + 255) / 256, blk, 0, stream>>>(ptmp, cls_tok, pos_emb, h, flag);

    const int MB4 = (Tt + 63) / 64;      // 13
    const int MB2 = (Tt + 31) / 32;      // 25
    const int MBS = (NSLOT + 63) / 64;   // 25 (worst-case expert load, FR=4)
    const int MBS2 = (NSLOT + 31) / 32;  // 50 (FR=2)

    for (int l = 0; l < Ll; l++) {
        int m = l / 2;
        // --- attention ---
        ln_kernel<<<Tt / 4, blk, 0, stream>>>(h, ln1_w, ln1_b, (size_t)l * Dd, y16, flag);
        if (use_cvt) {
            gemm2_kernel<2, 1><<<dim3(3 * Dd / 64, MB2), blk, 0, stream>>>(
                y16, wq + (size_t)l * 3 * Dd * Dd, bq + (size_t)l * 3 * Dd,
                nullptr, qkv16, Tt, 3 * Dd, Dd, 0);
        } else {
            gemm_kernel<4><<<dim3(3 * Dd / 64, MB4), blk, 0, stream>>>(
                y16, qkv_w, (size_t)l * 3 * Dd * Dd, qkv_b, (size_t)l * 3 * Dd,
                nullptr, qkv16, nullptr, Tt, 3 * Dd, Dd, 0, flag);
        }
        attn_kernel<<<dim3(4, 6, Bv), blk, 0, stream>>>(qkv16, att16);
        if (use_cvt) {
            // split-K=2, f32-atomic accumulate into h (h already holds residual)
            gemm2_kernel<2, 2><<<dim3(Dd / 64, MB2, 2), blk, 0, stream>>>(
                att16, wp + (size_t)l * Dd * Dd, bp + (size_t)l * Dd,
                h, nullptr, Tt, Dd, Dd, 0);
        } else {
            gemm_kernel<2><<<dim3(Dd / 64, MB2), blk, 0, stream>>>(
                att16, proj_w, (size_t)l * Dd * Dd, proj_b, (size_t)l * Dd,
                h, nullptr, h, Tt, Dd, Dd, 0, flag);
        }
        // --- ffn ---
        if (l % 2 == 0) {
            ln_kernel<<<Tt / 4, blk, 0, stream>>>(h, ln2_w, ln2_b, (size_t)l * Dd, y16, flag);
            if (use_cvt) {
                gemm2_kernel<2, 1><<<dim3(Hh / 64, MB2), blk, 0, stream>>>(
                    y16, w1c + (size_t)m * Hh * Dd, b1c + (size_t)m * Hh,
                    nullptr, hid16, Tt, Hh, Dd, 1);
                gemm2_kernel<2, 4><<<dim3(Dd / 64, MB2, 4), blk, 0, stream>>>(
                    hid16, w2c + (size_t)m * Dd * Hh, b2c + (size_t)m * Dd,
                    h, nullptr, Tt, Dd, Hh, 0);
            } else {
                gemm_kernel<4><<<dim3(Hh / 64, MB4), blk, 0, stream>>>(
                    y16, fc1_w, (size_t)m * Hh * Dd, fc1_b, (size_t)m * Hh,
                    nullptr, hid16, nullptr, Tt, Hh, Dd, 1, flag);
                gemm_kernel<2><<<dim3(Dd / 64, MB2), blk, 0, stream>>>(
                    hid16, fc2_w, (size_t)m * Dd * Hh, fc2_b, (size_t)m * Dd,
                    h, nullptr, h, Tt, Dd, Hh, 0, flag);
            }
        } else {
            if (use_cvt) {
                // fused ln2+gate -> sel/gw ; 1-block build -> cnt/perm
                ln_gate_kernel<<<Tt / 4, blk, 0, stream>>>(
                    h, ln2_w, ln2_b, (size_t)l * Dd, y16,
                    gate_w, (size_t)m * Ee * Dd, gw, sel, flag);
                build_kernel<<<1, blk, 0, stream>>>(sel, cnt, perm);
                moe2_kernel<4><<<dim3(Hh / 64, MBS, Ee), blk, 0, stream>>>(
                    y16, we1 + (size_t)m * Ee * Hh * Dd, be1 + (size_t)m * Ee * Hh,
                    nullptr, hid16, cnt, perm, Hh, Dd, 1, 1, nullptr, nullptr);
                // e2 with fused combine: h += gw[slot]*(acc+bias)
                moe2_kernel<2><<<dim3(Dd / 64, MBS2, Ee), blk, 0, stream>>>(
                    hid16, we2 + (size_t)m * Ee * Dd * Hh, be2 + (size_t)m * Ee * Dd,
                    nullptr, nullptr, cnt, perm, Dd, Hh, 0, 0, gw, h);
            } else {
                ln_kernel<<<Tt / 4, blk, 0, stream>>>(h, ln2_w, ln2_b, (size_t)l * Dd, y16, flag);
                hipMemsetAsync(cnt, 0, Ee * sizeof(int), stream);
                gate_kernel<<<Tt, 64, 0, stream>>>(
                    y16, gate_w, (size_t)m * Ee * Dd, gw, cnt, perm, flag);
                moe_gemm<<<dim3(Hh / 64, MBS, Ee), blk, 0, stream>>>(
                    y16, e1_w, (size_t)m * Ee * Hh * Dd, e1_b, (size_t)m * Ee * Hh,
                    nullptr, hid16, cnt, perm, Hh, Dd, 1, 1, flag);
                moe_gemm<<<dim3(Dd / 64, MBS, Ee), blk, 0, stream>>>(
                    hid16, e2_w, (size_t)m * Ee * Dd * Hh, e2_b, (size_t)m * Ee * Dd,
                    moeb, nullptr, cnt, perm, Dd, Hh, 0, 0, flag);
                moe_combine<<<(Tt * Dd + 255) / 256, blk, 0, stream>>>(h, moeb, gw);
            }
        }
    }

    if (use_cvt) {
        lncls_kernel<<<1, blk, 0, stream>>>(h, lnf_w, lnf_b, y16, flag);
    } else {
        ln_kernel<<<Tt / 4, blk, 0, stream>>>(h, lnf_w, lnf_b, 0, y16, flag);
    }
    head_kernel<<<(Bv * NCLS + 255) / 256, blk, 0, stream>>>(y16, head_w, head_b, d_out, flag);
}